// Round 1
// baseline (7005.156 us; speedup 1.0000x reference)
//
#include <hip/hip_runtime.h>

#define NN 10000
#define NE 320000
#define CHN 256
#define NHD 8
#define HDD 32

typedef float f4 __attribute__((ext_vector_type(4)));

__device__ __forceinline__ unsigned fkey(float f) {
  unsigned u = __float_as_uint(f);
  return (u & 0x80000000u) ? ~u : (u | 0x80000000u);
}
__device__ __forceinline__ float funkey(unsigned u) {
  return (u & 0x80000000u) ? __uint_as_float(u & 0x7fffffffu) : __uint_as_float(~u);
}

// Generic tiled f32 GEMM: C[M,Nc] = act(A[M,K] @ B[K,Nc] + bias (+ res))
__global__ __launch_bounds__(256) void gemm_k(
    const float* __restrict__ A, const float* __restrict__ B,
    const float* __restrict__ bias, const float* __restrict__ res,
    float* __restrict__ C, int M, int K, int Nc, int do_relu)
{
  __shared__ float As[16][64];
  __shared__ float Bs[16][64];
  const int t = threadIdx.x;
  const int tx = t & 15, ty = t >> 4;
  const int n0 = blockIdx.x * 64;
  const int m0 = blockIdx.y * 64;
  const int lm = t >> 2, lch = t & 3;
  const int bk = t >> 4, bn = t & 15;
  float acc[4][4] = {};
  for (int k0 = 0; k0 < K; k0 += 16) {
    f4 av = {0.f, 0.f, 0.f, 0.f};
    if (m0 + lm < M) av = *(const f4*)(A + (size_t)(m0 + lm) * K + k0 + lch * 4);
    f4 bv = *(const f4*)(B + (size_t)(k0 + bk) * Nc + n0 + bn * 4);
    __syncthreads();
    As[lch * 4 + 0][lm] = av[0];
    As[lch * 4 + 1][lm] = av[1];
    As[lch * 4 + 2][lm] = av[2];
    As[lch * 4 + 3][lm] = av[3];
    *(f4*)&Bs[bk][bn * 4] = bv;
    __syncthreads();
#pragma unroll
    for (int kk = 0; kk < 16; kk++) {
      f4 a = *(f4*)&As[kk][ty * 4];
      f4 b = *(f4*)&Bs[kk][tx * 4];
#pragma unroll
      for (int i = 0; i < 4; i++)
#pragma unroll
        for (int j = 0; j < 4; j++) acc[i][j] = fmaf(a[i], b[j], acc[i][j]);
    }
  }
#pragma unroll
  for (int i = 0; i < 4; i++) {
    const int gm = m0 + ty * 4 + i;
    if (gm < M) {
      f4 v;
#pragma unroll
      for (int j = 0; j < 4; j++) v[j] = acc[i][j] + bias[n0 + tx * 4 + j];
      if (res) {
        f4 rv = *(const f4*)(res + (size_t)gm * Nc + n0 + tx * 4);
#pragma unroll
        for (int j = 0; j < 4; j++) v[j] += rv[j];
      }
      if (do_relu) {
#pragma unroll
        for (int j = 0; j < 4; j++) v[j] = fmaxf(v[j], 0.f);
      }
      *(f4*)(C + (size_t)gm * Nc + n0 + tx * 4) = v;
    }
  }
}

// Per (head, 64-edge panel): Ex = edge_attr @ Ew[:,h*64:+64] + Eb, then
// conn = relu(sign(s2)sqrt|s2| + Kh[src]+Qh[dst]), score = conn . Aw, clip,
// store conn (into d_out eh region) + score, atomicMax segment max.
__global__ __launch_bounds__(256) void edge_conn_k(
    const float* __restrict__ EA, const float* __restrict__ Ew, const float* __restrict__ Eb,
    const float* __restrict__ Kh, const float* __restrict__ Qh,
    const int* __restrict__ ei, const float* __restrict__ Aw,
    float* __restrict__ conn, float* __restrict__ score, unsigned* __restrict__ mkey)
{
  __shared__ float As[16][64];
  __shared__ float Bs[16][64];
  __shared__ float Exl[64][68];
  const int t = threadIdx.x;
  const int tx = t & 15, ty = t >> 4;
  const int h = blockIdx.x;       // head fastest -> 8 blocks share the EA panel in L2
  const int e0 = blockIdx.y * 64;
  const int lm = t >> 2, lch = t & 3;
  const int bk = t >> 4, bn = t & 15;
  float acc[4][4] = {};
  for (int k0 = 0; k0 < 256; k0 += 16) {
    f4 av = *(const f4*)(EA + (size_t)(e0 + lm) * 256 + k0 + lch * 4);
    f4 bv = *(const f4*)(Ew + (size_t)(k0 + bk) * 512 + h * 64 + bn * 4);
    __syncthreads();
    As[lch * 4 + 0][lm] = av[0];
    As[lch * 4 + 1][lm] = av[1];
    As[lch * 4 + 2][lm] = av[2];
    As[lch * 4 + 3][lm] = av[3];
    *(f4*)&Bs[bk][bn * 4] = bv;
    __syncthreads();
#pragma unroll
    for (int kk = 0; kk < 16; kk++) {
      f4 a = *(f4*)&As[kk][ty * 4];
      f4 b = *(f4*)&Bs[kk][tx * 4];
#pragma unroll
      for (int i = 0; i < 4; i++)
#pragma unroll
        for (int j = 0; j < 4; j++) acc[i][j] = fmaf(a[i], b[j], acc[i][j]);
    }
  }
  __syncthreads();
#pragma unroll
  for (int i = 0; i < 4; i++) {
    f4 v;
#pragma unroll
    for (int j = 0; j < 4; j++) v[j] = acc[i][j] + Eb[h * 64 + tx * 4 + j];
    *(f4*)&Exl[ty * 4 + i][tx * 4] = v;
  }
  __syncthreads();
  const int m2 = t >> 2, dg = t & 3;
  const int e = e0 + m2;
  const int src = ei[e], dst = ei[NE + e];
  const int cb = h * 32 + dg * 8;
  f4 x1a = *(f4*)&Exl[m2][dg * 8];
  f4 x1b = *(f4*)&Exl[m2][dg * 8 + 4];
  f4 x2a = *(f4*)&Exl[m2][32 + dg * 8];
  f4 x2b = *(f4*)&Exl[m2][32 + dg * 8 + 4];
  f4 k1 = *(const f4*)(Kh + (size_t)src * 256 + cb);
  f4 k2 = *(const f4*)(Kh + (size_t)src * 256 + cb + 4);
  f4 q1 = *(const f4*)(Qh + (size_t)dst * 256 + cb);
  f4 q2 = *(const f4*)(Qh + (size_t)dst * 256 + cb + 4);
  f4 c1, c2;
  float part = 0.f;
#pragma unroll
  for (int j = 0; j < 4; j++) {
    float s2 = x1a[j] * x2a[j];
    float v = copysignf(sqrtf(fabsf(s2)), s2) + k1[j] + q1[j];
    v = fmaxf(v, 0.f);
    c1[j] = v;
    part += v * Aw[(dg * 8 + j) * 8 + h];
    float s2b = x1b[j] * x2b[j];
    float vb = copysignf(sqrtf(fabsf(s2b)), s2b) + k2[j] + q2[j];
    vb = fmaxf(vb, 0.f);
    c2[j] = vb;
    part += vb * Aw[(dg * 8 + 4 + j) * 8 + h];
  }
  *(f4*)(conn + (size_t)e * 256 + cb) = c1;
  *(f4*)(conn + (size_t)e * 256 + cb + 4) = c2;
  part += __shfl_xor(part, 1);
  part += __shfl_xor(part, 2);
  if (dg == 0) {
    float s = fminf(fmaxf(part, -5.f), 5.f);
    score[(size_t)e * 8 + h] = s;
    atomicMax(&mkey[dst * 8 + h], fkey(s));
  }
}

__global__ void expsum_k(const float* __restrict__ score, const int* __restrict__ ei,
                         const unsigned* __restrict__ mkey, float* __restrict__ ssum)
{
  int gid = blockIdx.x * 256 + threadIdx.x;   // NE*8 exact
  int e = gid >> 3, h = gid & 7;
  int dst = ei[NE + e];
  float m = funkey(mkey[dst * 8 + h]);
  atomicAdd(&ssum[dst * 8 + h], expf(score[gid] - m));
}

__global__ void agg_k(const float* __restrict__ score, const int* __restrict__ ei,
                      const unsigned* __restrict__ mkey, const float* __restrict__ ssum,
                      const float* __restrict__ Vh, const float* __restrict__ conn,
                      float* __restrict__ VoAcc, float* __restrict__ rowAcc)
{
  int gid = blockIdx.x * 256 + threadIdx.x;   // NE*32 exact
  int e = gid >> 5, p = gid & 31;
  int h = p >> 2, dg = p & 3;
  int dst = ei[NE + e], src = ei[e];
  float s = score[(size_t)e * 8 + h];
  float m = funkey(mkey[dst * 8 + h]);
  float attn = expf(s - m) / (ssum[dst * 8 + h] + 1e-16f);
  int cb = h * 32 + dg * 8;
  const float* vp = Vh + (size_t)src * 256 + cb;
  const float* cp = conn + (size_t)e * 256 + cb;
  float* vo = VoAcc + (size_t)dst * 256 + cb;
  float* ro = rowAcc + (size_t)dst * 256 + cb;
#pragma unroll
  for (int j = 0; j < 8; j++) {
    atomicAdd(&vo[j], vp[j] * attn);
    atomicAdd(&ro[j], cp[j] * attn);
  }
}

// Per node: rowV = rowAcc @ VeRow (per head), Vo = Qh + VoAcc + rowV, degree scaler.
__global__ __launch_bounds__(256) void node_epi_k(
    const float* __restrict__ Qh, const float* __restrict__ VoAcc,
    const float* __restrict__ rowAcc, const float* __restrict__ VeRow,
    const float* __restrict__ deg_coef, const float* __restrict__ log_deg,
    float* __restrict__ nh_a)
{
  const int n = blockIdx.x, t = threadIdx.x;
  __shared__ float rA[256];
  rA[t] = rowAcc[(size_t)n * 256 + t];
  __syncthreads();
  const int h = t >> 5;
  float acc = 0.f;
#pragma unroll
  for (int d = 0; d < 32; d++) acc = fmaf(rA[h * 32 + d], VeRow[d * 256 + t], acc);
  float v = Qh[(size_t)n * 256 + t] + VoAcc[(size_t)n * 256 + t] + acc;
  float ld = log_deg[n];
  v = v * (deg_coef[2 * t] + ld * deg_coef[2 * t + 1]);
  nh_a[(size_t)n * 256 + t] = v;
}

__global__ void bn_stats_k(const float* __restrict__ X, int R, float* __restrict__ st)
{
  int t = threadIdx.x;
  float s = 0.f, s2 = 0.f;
  for (int r = blockIdx.x; r < R; r += gridDim.x) {
    float v = X[(size_t)r * 256 + t];
    s += v;
    s2 += v * v;
  }
  atomicAdd(&st[t], s);
  atomicAdd(&st[256 + t], s2);
}

__global__ void bn_fin_k(float* __restrict__ st, float invR)
{
  int t = threadIdx.x;
  float mean = st[t] * invR;
  float var = st[256 + t] * invR - mean * mean;
  st[t] = mean;
  st[256 + t] = rsqrtf(var + 1e-5f);
}

__global__ void bn_apply_k(const float* __restrict__ X, float* __restrict__ Y,
                           const float* __restrict__ st, const float* __restrict__ g,
                           const float* __restrict__ b, int R)
{
  int t = threadIdx.x;
  float mean = st[t], rstd = st[256 + t], gg = g[t], bb = b[t];
  for (int r = blockIdx.x; r < R; r += gridDim.x) {
    Y[(size_t)r * 256 + t] = (X[(size_t)r * 256 + t] - mean) * rstd * gg + bb;
  }
}

// In-place per-64-row block: eh = conn @ Eow + Eob + edge_attr.
// Full conn block staged in LDS (two 128-k halves) before any overwrite.
__global__ __launch_bounds__(256) void eh_gemm_k(
    const float* __restrict__ Eow, const float* __restrict__ Eob,
    const float* __restrict__ EA, float* __restrict__ eh)
{
  __shared__ float As[128][64];
  __shared__ float Bs[16][64];
  const int t = threadIdx.x;
  const int tx = t & 15, ty = t >> 4;
  const int e0 = blockIdx.x * 64;
  const int bk = t >> 4, bn = t & 15;
  float acc[4][4][4] = {};
  for (int kh = 0; kh < 2; kh++) {
    __syncthreads();
    for (int it = 0; it < 8; it++) {
      int li = t + 256 * it;
      int m = li >> 5, ch = li & 31;
      f4 cv = *(const f4*)(eh + (size_t)(e0 + m) * 256 + kh * 128 + ch * 4);
      As[ch * 4 + 0][m] = cv[0];
      As[ch * 4 + 1][m] = cv[1];
      As[ch * 4 + 2][m] = cv[2];
      As[ch * 4 + 3][m] = cv[3];
    }
    __syncthreads();
    for (int ct = 0; ct < 4; ct++) {
      for (int kt = 0; kt < 8; kt++) {
        f4 bv = *(const f4*)(Eow + (size_t)(kh * 128 + kt * 16 + bk) * 256 + ct * 64 + bn * 4);
        __syncthreads();
        *(f4*)&Bs[bk][bn * 4] = bv;
        __syncthreads();
#pragma unroll
        for (int kk = 0; kk < 16; kk++) {
          f4 a = *(f4*)&As[kt * 16 + kk][ty * 4];
          f4 b = *(f4*)&Bs[kk][tx * 4];
#pragma unroll
          for (int i = 0; i < 4; i++)
#pragma unroll
            for (int j = 0; j < 4; j++) acc[ct][i][j] = fmaf(a[i], b[j], acc[ct][i][j]);
        }
      }
    }
  }
  __syncthreads();
#pragma unroll
  for (int ct = 0; ct < 4; ct++) {
    const int n0 = ct * 64;
#pragma unroll
    for (int i = 0; i < 4; i++) {
      const int e = e0 + ty * 4 + i;
      f4 rv = *(const f4*)(EA + (size_t)e * 256 + n0 + tx * 4);
      f4 v;
#pragma unroll
      for (int j = 0; j < 4; j++) v[j] = acc[ct][i][j] + Eob[n0 + tx * 4 + j] + rv[j];
      *(f4*)(eh + (size_t)e * 256 + n0 + tx * 4) = v;
    }
  }
}

extern "C" void kernel_launch(void* const* d_in, const int* in_sizes, int n_in,
                              void* d_out, int out_size, void* d_ws, size_t ws_size,
                              hipStream_t stream)
{
  (void)in_sizes; (void)n_in; (void)out_size; (void)ws_size;
  const float* x        = (const float*)d_in[0];
  const float* edge_attr= (const float*)d_in[1];
  const float* log_deg  = (const float*)d_in[2];
  const int*   ei       = (const int*)d_in[3];
  const float* Qw = (const float*)d_in[4];  const float* Qb = (const float*)d_in[5];
  const float* Kw = (const float*)d_in[6];  const float* Kb = (const float*)d_in[7];
  const float* Ew = (const float*)d_in[8];  const float* Eb = (const float*)d_in[9];
  const float* Vw = (const float*)d_in[10]; const float* Vb = (const float*)d_in[11];
  const float* Aw = (const float*)d_in[12]; const float* VeRow = (const float*)d_in[13];
  const float* deg_coef = (const float*)d_in[14];
  const float* Now = (const float*)d_in[15]; const float* Nob = (const float*)d_in[16];
  const float* Eow = (const float*)d_in[17]; const float* Eob = (const float*)d_in[18];
  const float* bn1n_g = (const float*)d_in[19]; const float* bn1n_b = (const float*)d_in[20];
  const float* bn1e_g = (const float*)d_in[21]; const float* bn1e_b = (const float*)d_in[22];
  const float* f1w = (const float*)d_in[23]; const float* f1b = (const float*)d_in[24];
  const float* f2w = (const float*)d_in[25]; const float* f2b = (const float*)d_in[26];
  const float* bn2_g = (const float*)d_in[27]; const float* bn2_b = (const float*)d_in[28];

  float* out_nh = (float*)d_out;
  float* out_eh = out_nh + (size_t)NN * 256;   // conn lives here first, becomes eh

  float* ws     = (float*)d_ws;
  float* Qh     = ws;
  float* Kh     = Qh + 2560000;
  float* Vh     = Kh + 2560000;
  float* VoAcc  = Vh + 2560000;
  float* rowAcc = VoAcc + 2560000;
  float* score  = rowAcc + 2560000;            // NE*8 = 2.56M
  unsigned* mkey= (unsigned*)(score + 2560000);// NN*8 = 80k
  float* ssum   = (float*)mkey + 80000;        // NN*8
  float* nh_a   = ssum + 80000;
  float* nh2    = nh_a + 2560000;
  float* ffn1   = nh2 + 2560000;               // NN*512 = 5.12M
  float* st1    = ffn1 + 5120000;
  float* st2    = st1 + 512;
  float* st3    = st2 + 512;

  hipMemsetAsync(VoAcc, 0, (size_t)2560000 * 4, stream);
  hipMemsetAsync(rowAcc, 0, (size_t)2560000 * 4, stream);
  hipMemsetAsync(mkey, 0, (size_t)80000 * 4, stream);
  hipMemsetAsync(ssum, 0, (size_t)80000 * 4, stream);
  hipMemsetAsync(st1, 0, (size_t)3 * 512 * 4, stream);

  dim3 blk(256);
  dim3 g_n256(256 / 64, (NN + 63) / 64);

  // QKV projections
  gemm_k<<<g_n256, blk, 0, stream>>>(x, Qw, Qb, nullptr, Qh, NN, 256, 256, 0);
  gemm_k<<<g_n256, blk, 0, stream>>>(x, Kw, Kb, nullptr, Kh, NN, 256, 256, 0);
  gemm_k<<<g_n256, blk, 0, stream>>>(x, Vw, Vb, nullptr, Vh, NN, 256, 256, 0);

  // edge conn + score + segment max
  edge_conn_k<<<dim3(8, NE / 64), blk, 0, stream>>>(edge_attr, Ew, Eb, Kh, Qh, ei, Aw,
                                                    out_eh, score, mkey);
  // segment exp-sum
  expsum_k<<<dim3(NE * 8 / 256), blk, 0, stream>>>(score, ei, mkey, ssum);
  // scatter-aggregate messages
  agg_k<<<dim3(NE * 32 / 256), blk, 0, stream>>>(score, ei, mkey, ssum, Vh, out_eh,
                                                 VoAcc, rowAcc);
  // node epilogue: rowV einsum + Qh + VoAcc + degree scaler
  node_epi_k<<<dim3(NN), blk, 0, stream>>>(Qh, VoAcc, rowAcc, VeRow, deg_coef, log_deg, nh_a);

  // nh1 = nh_a @ Now + Nob + x  -> d_out nh region
  gemm_k<<<g_n256, blk, 0, stream>>>(nh_a, Now, Nob, x, out_nh, NN, 256, 256, 0);
  // BN1 node
  bn_stats_k<<<dim3(512), blk, 0, stream>>>(out_nh, NN, st1);
  bn_fin_k<<<dim3(1), blk, 0, stream>>>(st1, 1.0f / NN);
  bn_apply_k<<<dim3(512), blk, 0, stream>>>(out_nh, nh2, st1, bn1n_g, bn1n_b, NN);
  // FFN
  gemm_k<<<dim3(512 / 64, (NN + 63) / 64), blk, 0, stream>>>(nh2, f1w, f1b, nullptr, ffn1,
                                                             NN, 256, 512, 1);
  gemm_k<<<g_n256, blk, 0, stream>>>(ffn1, f2w, f2b, nh2, out_nh, NN, 512, 256, 0);
  // BN2 node (in place)
  bn_stats_k<<<dim3(512), blk, 0, stream>>>(out_nh, NN, st2);
  bn_fin_k<<<dim3(1), blk, 0, stream>>>(st2, 1.0f / NN);
  bn_apply_k<<<dim3(512), blk, 0, stream>>>(out_nh, out_nh, st2, bn2_g, bn2_b, NN);

  // eh = conn @ Eow + Eob + edge_attr, in place in d_out eh region
  eh_gemm_k<<<dim3(NE / 64), blk, 0, stream>>>(Eow, Eob, edge_attr, out_eh);
  // BN1 edge (in place)
  bn_stats_k<<<dim3(1024), blk, 0, stream>>>(out_eh, NE, st3);
  bn_fin_k<<<dim3(1), blk, 0, stream>>>(st3, 1.0f / NE);
  bn_apply_k<<<dim3(1024), blk, 0, stream>>>(out_eh, out_eh, st3, bn1e_g, bn1e_b, NE);
}

// Round 2
// 2721.540 us; speedup vs baseline: 2.5740x; 2.5740x over previous
//
#include <hip/hip_runtime.h>

#define NN 10000
#define NE 320000

typedef float f4 __attribute__((ext_vector_type(4)));

// Generic tiled f32 GEMM: C[M,Nc] = act(A[M,K] @ B[K,Nc] + bias (+ res))
__global__ __launch_bounds__(256) void gemm_k(
    const float* __restrict__ A, const float* __restrict__ B,
    const float* __restrict__ bias, const float* __restrict__ res,
    float* __restrict__ C, int M, int K, int Nc, int do_relu)
{
  __shared__ float As[16][64];
  __shared__ float Bs[16][64];
  const int t = threadIdx.x;
  const int tx = t & 15, ty = t >> 4;
  const int n0 = blockIdx.x * 64;
  const int m0 = blockIdx.y * 64;
  const int lm = t >> 2, lch = t & 3;
  const int bk = t >> 4, bn = t & 15;
  float acc[4][4] = {};
  for (int k0 = 0; k0 < K; k0 += 16) {
    f4 av = {0.f, 0.f, 0.f, 0.f};
    if (m0 + lm < M) av = *(const f4*)(A + (size_t)(m0 + lm) * K + k0 + lch * 4);
    f4 bv = *(const f4*)(B + (size_t)(k0 + bk) * Nc + n0 + bn * 4);
    __syncthreads();
    As[lch * 4 + 0][lm] = av[0];
    As[lch * 4 + 1][lm] = av[1];
    As[lch * 4 + 2][lm] = av[2];
    As[lch * 4 + 3][lm] = av[3];
    *(f4*)&Bs[bk][bn * 4] = bv;
    __syncthreads();
#pragma unroll
    for (int kk = 0; kk < 16; kk++) {
      f4 a = *(f4*)&As[kk][ty * 4];
      f4 b = *(f4*)&Bs[kk][tx * 4];
#pragma unroll
      for (int i = 0; i < 4; i++)
#pragma unroll
        for (int j = 0; j < 4; j++) acc[i][j] = fmaf(a[i], b[j], acc[i][j]);
    }
  }
#pragma unroll
  for (int i = 0; i < 4; i++) {
    const int gm = m0 + ty * 4 + i;
    if (gm < M) {
      f4 v;
#pragma unroll
      for (int j = 0; j < 4; j++) v[j] = acc[i][j] + bias[n0 + tx * 4 + j];
      if (res) {
        f4 rv = *(const f4*)(res + (size_t)gm * Nc + n0 + tx * 4);
#pragma unroll
        for (int j = 0; j < 4; j++) v[j] += rv[j];
      }
      if (do_relu) {
#pragma unroll
        for (int j = 0; j < 4; j++) v[j] = fmaxf(v[j], 0.f);
      }
      *(f4*)(C + (size_t)gm * Nc + n0 + tx * 4) = v;
    }
  }
}

// Per (head, 64-edge panel): Ex = edge_attr @ Ew[:,h*64:+64] + Eb, then
// conn = relu(sign(s2)sqrt|s2| + Kh[src]+Qh[dst]), score = conn . Aw, clip,
// store conn (into d_out eh region) + score.
__global__ __launch_bounds__(256) void edge_conn_k(
    const float* __restrict__ EA, const float* __restrict__ Ew, const float* __restrict__ Eb,
    const float* __restrict__ Kh, const float* __restrict__ Qh,
    const int* __restrict__ ei, const float* __restrict__ Aw,
    float* __restrict__ conn, float* __restrict__ score)
{
  __shared__ float As[16][64];
  __shared__ float Bs[16][64];
  __shared__ float Exl[64][68];
  const int t = threadIdx.x;
  const int tx = t & 15, ty = t >> 4;
  const int h = blockIdx.x;       // head fastest -> 8 blocks share the EA panel in L2
  const int e0 = blockIdx.y * 64;
  const int lm = t >> 2, lch = t & 3;
  const int bk = t >> 4, bn = t & 15;
  float acc[4][4] = {};
  for (int k0 = 0; k0 < 256; k0 += 16) {
    f4 av = *(const f4*)(EA + (size_t)(e0 + lm) * 256 + k0 + lch * 4);
    f4 bv = *(const f4*)(Ew + (size_t)(k0 + bk) * 512 + h * 64 + bn * 4);
    __syncthreads();
    As[lch * 4 + 0][lm] = av[0];
    As[lch * 4 + 1][lm] = av[1];
    As[lch * 4 + 2][lm] = av[2];
    As[lch * 4 + 3][lm] = av[3];
    *(f4*)&Bs[bk][bn * 4] = bv;
    __syncthreads();
#pragma unroll
    for (int kk = 0; kk < 16; kk++) {
      f4 a = *(f4*)&As[kk][ty * 4];
      f4 b = *(f4*)&Bs[kk][tx * 4];
#pragma unroll
      for (int i = 0; i < 4; i++)
#pragma unroll
        for (int j = 0; j < 4; j++) acc[i][j] = fmaf(a[i], b[j], acc[i][j]);
    }
  }
  __syncthreads();
#pragma unroll
  for (int i = 0; i < 4; i++) {
    f4 v;
#pragma unroll
    for (int j = 0; j < 4; j++) v[j] = acc[i][j] + Eb[h * 64 + tx * 4 + j];
    *(f4*)&Exl[ty * 4 + i][tx * 4] = v;
  }
  __syncthreads();
  const int m2 = t >> 2, dg = t & 3;
  const int e = e0 + m2;
  const int src = ei[e], dst = ei[NE + e];
  const int cb = h * 32 + dg * 8;
  f4 x1a = *(f4*)&Exl[m2][dg * 8];
  f4 x1b = *(f4*)&Exl[m2][dg * 8 + 4];
  f4 x2a = *(f4*)&Exl[m2][32 + dg * 8];
  f4 x2b = *(f4*)&Exl[m2][32 + dg * 8 + 4];
  f4 k1 = *(const f4*)(Kh + (size_t)src * 256 + cb);
  f4 k2 = *(const f4*)(Kh + (size_t)src * 256 + cb + 4);
  f4 q1 = *(const f4*)(Qh + (size_t)dst * 256 + cb);
  f4 q2 = *(const f4*)(Qh + (size_t)dst * 256 + cb + 4);
  f4 c1, c2;
  float part = 0.f;
#pragma unroll
  for (int j = 0; j < 4; j++) {
    float s2 = x1a[j] * x2a[j];
    float v = copysignf(sqrtf(fabsf(s2)), s2) + k1[j] + q1[j];
    v = fmaxf(v, 0.f);
    c1[j] = v;
    part += v * Aw[(dg * 8 + j) * 8 + h];
    float s2b = x1b[j] * x2b[j];
    float vb = copysignf(sqrtf(fabsf(s2b)), s2b) + k2[j] + q2[j];
    vb = fmaxf(vb, 0.f);
    c2[j] = vb;
    part += vb * Aw[(dg * 8 + 4 + j) * 8 + h];
  }
  *(f4*)(conn + (size_t)e * 256 + cb) = c1;
  *(f4*)(conn + (size_t)e * 256 + cb + 4) = c2;
  part += __shfl_xor(part, 1);
  part += __shfl_xor(part, 2);
  if (dg == 0) {
    score[(size_t)e * 8 + h] = fminf(fmaxf(part, -5.f), 5.f);
  }
}

// ---------- CSR build (by destination) ----------
__global__ void hist_k(const int* __restrict__ ei, int* __restrict__ cnt)
{
  int e = blockIdx.x * 256 + threadIdx.x;
  if (e < NE) atomicAdd(&cnt[ei[NE + e]], 1);
}

__global__ __launch_bounds__(256) void scan_k(const int* __restrict__ cnt, int* __restrict__ off)
{
  __shared__ int part[256];
  const int t = threadIdx.x;
  const int PER = 40;                 // 256*40 = 10240 >= NN
  const int base = t * PER;
  int s = 0;
  for (int i = 0; i < PER; i++) {
    int b = base + i;
    if (b < NN) s += cnt[b];
  }
  part[t] = s;
  __syncthreads();
  for (int d = 1; d < 256; d <<= 1) {
    int v = (t >= d) ? part[t - d] : 0;
    __syncthreads();
    part[t] += v;
    __syncthreads();
  }
  int run = (t == 0) ? 0 : part[t - 1];
  for (int i = 0; i < PER; i++) {
    int b = base + i;
    if (b < NN) { off[b] = run; run += cnt[b]; }
  }
  if (t == 255) off[NN] = run;
}

__global__ void scat_k(const int* __restrict__ ei, const int* __restrict__ off,
                       int* __restrict__ cur, int* __restrict__ elist)
{
  int e = blockIdx.x * 256 + threadIdx.x;
  if (e < NE) {
    int d = ei[NE + e];
    int p = atomicAdd(&cur[d], 1);
    elist[off[d] + p] = e;
  }
}

// One block per node: segment softmax (online) + weighted aggregation of
// Vh[src] and conn[e], then rowV einsum + Qh + degree scaler -> nh_a.
__global__ __launch_bounds__(256) void node_agg_k(
    const int* __restrict__ off, const int* __restrict__ elist,
    const int* __restrict__ ei, const float* __restrict__ score,
    const float* __restrict__ Vh, const float* __restrict__ conn,
    const float* __restrict__ Qh, const float* __restrict__ VeRow,
    const float* __restrict__ deg_coef, const float* __restrict__ log_deg,
    float* __restrict__ nh_a)
{
  const int n = blockIdx.x, t = threadIdx.x;
  const int h = t >> 5;
  __shared__ int eL[128];
  __shared__ int srcL[128];
  __shared__ float sS[128 * 8];
  __shared__ float rA[256];
  const int start = off[n];
  const int deg = off[n + 1] - start;
  float m = -1e30f, ssum = 0.f, vo = 0.f, ro = 0.f;
  for (int c0 = 0; c0 < deg; c0 += 128) {
    const int cn = min(128, deg - c0);
    __syncthreads();
    if (t < cn) {
      int e = elist[start + c0 + t];
      eL[t] = e;
      srcL[t] = ei[e];
    }
    __syncthreads();
    for (int i = t; i < cn * 8; i += 256) sS[i] = score[(size_t)eL[i >> 3] * 8 + (i & 7)];
    __syncthreads();
    float mc = -1e30f;
    for (int i = 0; i < cn; i++) mc = fmaxf(mc, sS[i * 8 + h]);
    float nm = fmaxf(m, mc);
    float sc = __expf(m - nm);        // first chunk: exp(-huge) = 0
    ssum *= sc; vo *= sc; ro *= sc;
    m = nm;
    for (int i = 0; i < cn; i++) {
      float w = __expf(sS[i * 8 + h] - m);
      ssum += w;
      vo = fmaf(w, Vh[(size_t)srcL[i] * 256 + t], vo);
      ro = fmaf(w, conn[(size_t)eL[i] * 256 + t], ro);
    }
  }
  const float inv = 1.f / (ssum + 1e-16f);
  vo *= inv;
  ro *= inv;
  __syncthreads();
  rA[t] = ro;
  __syncthreads();
  float acc = 0.f;
#pragma unroll
  for (int d = 0; d < 32; d++) acc = fmaf(rA[h * 32 + d], VeRow[d * 256 + t], acc);
  float v = Qh[(size_t)n * 256 + t] + vo + acc;
  const float ld = log_deg[n];
  v = v * (deg_coef[2 * t] + ld * deg_coef[2 * t + 1]);
  nh_a[(size_t)n * 256 + t] = v;
}

__global__ void bn_stats_k(const float* __restrict__ X, int R, float* __restrict__ st)
{
  int t = threadIdx.x;
  float s = 0.f, s2 = 0.f;
  for (int r = blockIdx.x; r < R; r += gridDim.x) {
    float v = X[(size_t)r * 256 + t];
    s += v;
    s2 += v * v;
  }
  atomicAdd(&st[t], s);
  atomicAdd(&st[256 + t], s2);
}

__global__ void bn_fin_k(float* __restrict__ st, float invR)
{
  int t = threadIdx.x;
  float mean = st[t] * invR;
  float var = st[256 + t] * invR - mean * mean;
  st[t] = mean;
  st[256 + t] = rsqrtf(var + 1e-5f);
}

__global__ void bn_apply_k(const float* __restrict__ X, float* __restrict__ Y,
                           const float* __restrict__ st, const float* __restrict__ g,
                           const float* __restrict__ b, int R)
{
  int t = threadIdx.x;
  float mean = st[t], rstd = st[256 + t], gg = g[t], bb = b[t];
  for (int r = blockIdx.x; r < R; r += gridDim.x) {
    Y[(size_t)r * 256 + t] = (X[(size_t)r * 256 + t] - mean) * rstd * gg + bb;
  }
}

// In-place per-64-row block: eh = conn @ Eow + Eob + edge_attr.
// Full conn block staged in LDS (two 128-k halves) before any overwrite.
__global__ __launch_bounds__(256) void eh_gemm_k(
    const float* __restrict__ Eow, const float* __restrict__ Eob,
    const float* __restrict__ EA, float* __restrict__ eh)
{
  __shared__ float As[128][64];
  __shared__ float Bs[16][64];
  const int t = threadIdx.x;
  const int tx = t & 15, ty = t >> 4;
  const int e0 = blockIdx.x * 64;
  const int bk = t >> 4, bn = t & 15;
  float acc[4][4][4] = {};
  for (int kh = 0; kh < 2; kh++) {
    __syncthreads();
    for (int it = 0; it < 8; it++) {
      int li = t + 256 * it;
      int m = li >> 5, ch = li & 31;
      f4 cv = *(const f4*)(eh + (size_t)(e0 + m) * 256 + kh * 128 + ch * 4);
      As[ch * 4 + 0][m] = cv[0];
      As[ch * 4 + 1][m] = cv[1];
      As[ch * 4 + 2][m] = cv[2];
      As[ch * 4 + 3][m] = cv[3];
    }
    __syncthreads();
    for (int ct = 0; ct < 4; ct++) {
      for (int kt = 0; kt < 8; kt++) {
        f4 bv = *(const f4*)(Eow + (size_t)(kh * 128 + kt * 16 + bk) * 256 + ct * 64 + bn * 4);
        __syncthreads();
        *(f4*)&Bs[bk][bn * 4] = bv;
        __syncthreads();
#pragma unroll
        for (int kk = 0; kk < 16; kk++) {
          f4 a = *(f4*)&As[kt * 16 + kk][ty * 4];
          f4 b = *(f4*)&Bs[kk][tx * 4];
#pragma unroll
          for (int i = 0; i < 4; i++)
#pragma unroll
            for (int j = 0; j < 4; j++) acc[ct][i][j] = fmaf(a[i], b[j], acc[ct][i][j]);
        }
      }
    }
  }
  __syncthreads();
#pragma unroll
  for (int ct = 0; ct < 4; ct++) {
    const int n0 = ct * 64;
#pragma unroll
    for (int i = 0; i < 4; i++) {
      const int e = e0 + ty * 4 + i;
      f4 rv = *(const f4*)(EA + (size_t)e * 256 + n0 + tx * 4);
      f4 v;
#pragma unroll
      for (int j = 0; j < 4; j++) v[j] = acc[ct][i][j] + Eob[n0 + tx * 4 + j] + rv[j];
      *(f4*)(eh + (size_t)e * 256 + n0 + tx * 4) = v;
    }
  }
}

extern "C" void kernel_launch(void* const* d_in, const int* in_sizes, int n_in,
                              void* d_out, int out_size, void* d_ws, size_t ws_size,
                              hipStream_t stream)
{
  (void)in_sizes; (void)n_in; (void)out_size; (void)ws_size;
  const float* x        = (const float*)d_in[0];
  const float* edge_attr= (const float*)d_in[1];
  const float* log_deg  = (const float*)d_in[2];
  const int*   ei       = (const int*)d_in[3];
  const float* Qw = (const float*)d_in[4];  const float* Qb = (const float*)d_in[5];
  const float* Kw = (const float*)d_in[6];  const float* Kb = (const float*)d_in[7];
  const float* Ew = (const float*)d_in[8];  const float* Eb = (const float*)d_in[9];
  const float* Vw = (const float*)d_in[10]; const float* Vb = (const float*)d_in[11];
  const float* Aw = (const float*)d_in[12]; const float* VeRow = (const float*)d_in[13];
  const float* deg_coef = (const float*)d_in[14];
  const float* Now = (const float*)d_in[15]; const float* Nob = (const float*)d_in[16];
  const float* Eow = (const float*)d_in[17]; const float* Eob = (const float*)d_in[18];
  const float* bn1n_g = (const float*)d_in[19]; const float* bn1n_b = (const float*)d_in[20];
  const float* bn1e_g = (const float*)d_in[21]; const float* bn1e_b = (const float*)d_in[22];
  const float* f1w = (const float*)d_in[23]; const float* f1b = (const float*)d_in[24];
  const float* f2w = (const float*)d_in[25]; const float* f2b = (const float*)d_in[26];
  const float* bn2_g = (const float*)d_in[27]; const float* bn2_b = (const float*)d_in[28];

  float* out_nh = (float*)d_out;
  float* out_eh = out_nh + (size_t)NN * 256;   // conn lives here first, becomes eh

  float* ws     = (float*)d_ws;
  float* Qh     = ws;
  float* Kh     = Qh + 2560000;
  float* Vh     = Kh + 2560000;
  float* score  = Vh + 2560000;                // NE*8 = 2.56M
  float* nh_a   = score + 2560000;
  float* nh2    = nh_a + 2560000;
  float* ffn1   = nh2 + 2560000;               // NN*512 = 5.12M
  float* st1    = ffn1 + 5120000;
  float* st2    = st1 + 512;
  float* st3    = st2 + 512;
  int*   cnt    = (int*)(st3 + 512);
  int*   off    = cnt + NN;                    // NN+1
  int*   cur    = off + NN + 1;
  int*   elist  = cur + NN;                    // NE

  hipMemsetAsync(cnt, 0, (size_t)NN * 4, stream);
  hipMemsetAsync(cur, 0, (size_t)NN * 4, stream);
  hipMemsetAsync(st1, 0, (size_t)3 * 512 * 4, stream);

  dim3 blk(256);
  dim3 g_n256(256 / 64, (NN + 63) / 64);

  // CSR build (independent of GEMMs, cheap)
  hist_k<<<dim3(NE / 256), blk, 0, stream>>>(ei, cnt);
  scan_k<<<dim3(1), blk, 0, stream>>>(cnt, off);
  scat_k<<<dim3(NE / 256), blk, 0, stream>>>(ei, off, cur, elist);

  // QKV projections
  gemm_k<<<g_n256, blk, 0, stream>>>(x, Qw, Qb, nullptr, Qh, NN, 256, 256, 0);
  gemm_k<<<g_n256, blk, 0, stream>>>(x, Kw, Kb, nullptr, Kh, NN, 256, 256, 0);
  gemm_k<<<g_n256, blk, 0, stream>>>(x, Vw, Vb, nullptr, Vh, NN, 256, 256, 0);

  // edge conn + score
  edge_conn_k<<<dim3(8, NE / 64), blk, 0, stream>>>(edge_attr, Ew, Eb, Kh, Qh, ei, Aw,
                                                    out_eh, score);

  // per-node segment softmax + aggregation + rowV einsum + degree scaler
  node_agg_k<<<dim3(NN), blk, 0, stream>>>(off, elist, ei, score, Vh, out_eh,
                                           Qh, VeRow, deg_coef, log_deg, nh_a);

  // nh1 = nh_a @ Now + Nob + x  -> d_out nh region
  gemm_k<<<g_n256, blk, 0, stream>>>(nh_a, Now, Nob, x, out_nh, NN, 256, 256, 0);
  // BN1 node
  bn_stats_k<<<dim3(512), blk, 0, stream>>>(out_nh, NN, st1);
  bn_fin_k<<<dim3(1), blk, 0, stream>>>(st1, 1.0f / NN);
  bn_apply_k<<<dim3(512), blk, 0, stream>>>(out_nh, nh2, st1, bn1n_g, bn1n_b, NN);
  // FFN
  gemm_k<<<dim3(512 / 64, (NN + 63) / 64), blk, 0, stream>>>(nh2, f1w, f1b, nullptr, ffn1,
                                                             NN, 256, 512, 1);
  gemm_k<<<g_n256, blk, 0, stream>>>(ffn1, f2w, f2b, nh2, out_nh, NN, 512, 256, 0);
  // BN2 node (in place)
  bn_stats_k<<<dim3(512), blk, 0, stream>>>(out_nh, NN, st2);
  bn_fin_k<<<dim3(1), blk, 0, stream>>>(st2, 1.0f / NN);
  bn_apply_k<<<dim3(512), blk, 0, stream>>>(out_nh, out_nh, st2, bn2_g, bn2_b, NN);

  // eh = conn @ Eow + Eob + edge_attr, in place in d_out eh region
  eh_gemm_k<<<dim3(NE / 64), blk, 0, stream>>>(Eow, Eob, edge_attr, out_eh);
  // BN1 edge (in place)
  bn_stats_k<<<dim3(1024), blk, 0, stream>>>(out_eh, NE, st3);
  bn_fin_k<<<dim3(1), blk, 0, stream>>>(st3, 1.0f / NE);
  bn_apply_k<<<dim3(1024), blk, 0, stream>>>(out_eh, out_eh, st3, bn1e_g, bn1e_b, NE);
}

// Round 3
// 1045.026 us; speedup vs baseline: 6.7033x; 2.6043x over previous
//
#include <hip/hip_runtime.h>

#define NN 10000
#define NE 320000

typedef float f4 __attribute__((ext_vector_type(4)));
typedef float f32x4 __attribute__((ext_vector_type(4)));
typedef short bf16x8 __attribute__((ext_vector_type(8)));

__device__ __forceinline__ unsigned short f2b(float f) {
  unsigned u = __float_as_uint(f);
  u += 0x7fff + ((u >> 16) & 1);          // RNE
  return (unsigned short)(u >> 16);
}
__device__ __forceinline__ float b2f(unsigned short s) {
  return __uint_as_float(((unsigned)s) << 16);
}
__device__ __forceinline__ bf16x8 pack8(f4 a, f4 b) {
  bf16x8 r;
  r[0] = (short)f2b(a[0]); r[1] = (short)f2b(a[1]);
  r[2] = (short)f2b(a[2]); r[3] = (short)f2b(a[3]);
  r[4] = (short)f2b(b[0]); r[5] = (short)f2b(b[1]);
  r[6] = (short)f2b(b[2]); r[7] = (short)f2b(b[3]);
  return r;
}
// swizzled ushort index into a flat [64][256] bf16 tile (XOR bank swizzle)
__device__ __forceinline__ int swz(int row, int k) {
  return (row * 256 + k) ^ ((row & 7) << 3);
}

// transpose+cast weights: in f32 [K][N] -> out bf16 [N][K]
__global__ void castw_k(const float* __restrict__ in, unsigned short* __restrict__ out,
                        int K, int lg)
{
  int idx = blockIdx.x * 256 + threadIdx.x;
  if (idx >= (K << lg)) return;
  int n = idx & ((1 << lg) - 1), k = idx >> lg;
  out[(size_t)n * K + k] = f2b(in[idx]);
}

// Generic node-side MFMA GEMM: C[M,N] = act(castbf16(A[M,K]) @ BT^T + bias (+res))
// BT is bf16 [N][K]. BM=64 (4 waves, 16-row strips), BN=128. flags: 1=relu, 2=stats.
__global__ __launch_bounds__(256) void gemm_bf16_k(
    const float* __restrict__ A, const unsigned short* __restrict__ BT,
    const float* __restrict__ bias, const float* __restrict__ res,
    float* __restrict__ C, float* __restrict__ stats,
    int M, int K, int NT, int flags)
{
  __shared__ unsigned short Al[64][40];
  __shared__ unsigned short Bl[128][40];
  const int t = threadIdx.x;
  const int n0 = blockIdx.x * 128;
  const int m0 = blockIdx.y * 64;
  const int lane = t & 63, c = lane & 15, g = lane >> 4, w = t >> 6;
  f32x4 acc[8] = {};
  for (int k0 = 0; k0 < K; k0 += 32) {
    // stage A 64x32 (cast f32->bf16)
    {
      int row = t >> 2, kk = (t & 3) * 8;
      f4 v0 = {0.f,0.f,0.f,0.f}, v1 = {0.f,0.f,0.f,0.f};
      if (m0 + row < M) {
        const f4* p = (const f4*)(A + (size_t)(m0 + row) * K + k0 + kk);
        v0 = p[0]; v1 = p[1];
      }
      __syncthreads();
      *(bf16x8*)&Al[row][kk] = pack8(v0, v1);
    }
    // stage B 128x32
    {
      int col = t >> 1, kk = (t & 1) * 16;
      const bf16x8* p = (const bf16x8*)(BT + (size_t)(n0 + col) * K + k0 + kk);
      *(bf16x8*)&Bl[col][kk] = p[0];
      *(bf16x8*)&Bl[col][kk + 8] = p[1];
    }
    __syncthreads();
    bf16x8 a = *(bf16x8*)&Al[w * 16 + c][g * 8];
#pragma unroll
    for (int nb = 0; nb < 8; nb++) {
      bf16x8 b = *(bf16x8*)&Bl[nb * 16 + c][g * 8];
      acc[nb] = __builtin_amdgcn_mfma_f32_16x16x32_bf16(a, b, acc[nb], 0, 0, 0);
    }
  }
  const int do_relu = flags & 1, do_stats = flags & 2;
#pragma unroll
  for (int nb = 0; nb < 8; nb++) {
    const int col = n0 + nb * 16 + c;
    const float bs = bias[col];
    float sn = 0.f, qn = 0.f;
#pragma unroll
    for (int r = 0; r < 4; r++) {
      int row = m0 + w * 16 + g * 4 + r;
      if (row < M) {
        float v = acc[nb][r] + bs;
        if (res) v += res[(size_t)row * NT + col];
        if (do_relu) v = fmaxf(v, 0.f);
        C[(size_t)row * NT + col] = v;
        sn += v; qn += v * v;
      }
    }
    if (do_stats) {
      sn += __shfl_xor(sn, 16); sn += __shfl_xor(sn, 32);
      qn += __shfl_xor(qn, 16); qn += __shfl_xor(qn, 32);
      if (g == 0) {
        atomicAdd(&stats[col], sn);
        atomicAdd(&stats[NT + col], qn);
      }
    }
  }
}

// Edge kernel: per 64-edge panel, for each head h: Ex(:,h*64:+64) = EA@Ew + Eb via MFMA,
// then conn/score epilogue. conn written f32 into d_out eh region.
__global__ __launch_bounds__(256) void edge_conn_k(
    const float* __restrict__ EA, const unsigned short* __restrict__ EwT,
    const float* __restrict__ Eb, const float* __restrict__ Kh,
    const float* __restrict__ Qh, const int* __restrict__ ei,
    const float* __restrict__ Aw, float* __restrict__ conn, float* __restrict__ score)
{
  __shared__ unsigned short Abuf[16384];   // 64x256 bf16, swizzled
  __shared__ unsigned short Bbuf[16384];   // 64x256 bf16, swizzled; reused as Exl f32[64][68]
  float* Exl = (float*)Bbuf;
  const int t = threadIdx.x;
  const int e0 = blockIdx.x * 64;
  const int lane = t & 63, c = lane & 15, g = lane >> 4, w = t >> 6;
  // stage A = edge_attr tile (cast f32->bf16)
#pragma unroll
  for (int it = 0; it < 8; it++) {
    int o = t + it * 256;
    int row = o >> 5, kk = (o & 31) * 8;
    const f4* p = (const f4*)(EA + (size_t)(e0 + row) * 256 + kk);
    f4 v0 = p[0], v1 = p[1];
    *(bf16x8*)&Abuf[swz(row, kk)] = pack8(v0, v1);
  }
  const int m2 = t >> 2, dg = t & 3;
  const int e = e0 + m2;
  const int src = ei[e], dst = ei[NE + e];
  for (int h = 0; h < 8; h++) {
    __syncthreads();   // prev epilogue done with Exl (and h=0: A ready)
#pragma unroll
    for (int it = 0; it < 8; it++) {
      int o = t + it * 256;
      int row = o >> 5, kk = (o & 31) * 8;
      *(bf16x8*)&Bbuf[swz(row, kk)] =
          *(const bf16x8*)(EwT + (size_t)(h * 64 + row) * 256 + kk);
    }
    __syncthreads();
    f32x4 acc[4] = {};
#pragma unroll
    for (int ks = 0; ks < 8; ks++) {
      bf16x8 a = *(bf16x8*)&Abuf[swz(w * 16 + c, ks * 32 + g * 8)];
#pragma unroll
      for (int cb = 0; cb < 4; cb++) {
        bf16x8 b = *(bf16x8*)&Bbuf[swz(cb * 16 + c, ks * 32 + g * 8)];
        acc[cb] = __builtin_amdgcn_mfma_f32_16x16x32_bf16(a, b, acc[cb], 0, 0, 0);
      }
    }
    __syncthreads();   // all mfma reads of Bbuf done
#pragma unroll
    for (int cb = 0; cb < 4; cb++) {
      float eb = Eb[h * 64 + cb * 16 + c];
#pragma unroll
      for (int r = 0; r < 4; r++)
        Exl[(w * 16 + g * 4 + r) * 68 + cb * 16 + c] = acc[cb][r] + eb;
    }
    __syncthreads();
    // epilogue: conn + score for head h
    const int cb2 = h * 32 + dg * 8;
    const float* ex = Exl + m2 * 68;
    f4 x1a = *(const f4*)(ex + dg * 8);
    f4 x1b = *(const f4*)(ex + dg * 8 + 4);
    f4 x2a = *(const f4*)(ex + 32 + dg * 8);
    f4 x2b = *(const f4*)(ex + 32 + dg * 8 + 4);
    f4 k1 = *(const f4*)(Kh + (size_t)src * 256 + cb2);
    f4 k2 = *(const f4*)(Kh + (size_t)src * 256 + cb2 + 4);
    f4 q1 = *(const f4*)(Qh + (size_t)dst * 256 + cb2);
    f4 q2 = *(const f4*)(Qh + (size_t)dst * 256 + cb2 + 4);
    f4 c1, c2;
    float part = 0.f;
#pragma unroll
    for (int j = 0; j < 4; j++) {
      float s2 = x1a[j] * x2a[j];
      float v = copysignf(sqrtf(fabsf(s2)), s2) + k1[j] + q1[j];
      v = fmaxf(v, 0.f);
      c1[j] = v;
      part += v * Aw[(dg * 8 + j) * 8 + h];
      float s2b = x1b[j] * x2b[j];
      float vb = copysignf(sqrtf(fabsf(s2b)), s2b) + k2[j] + q2[j];
      vb = fmaxf(vb, 0.f);
      c2[j] = vb;
      part += vb * Aw[(dg * 8 + 4 + j) * 8 + h];
    }
    *(f4*)(conn + (size_t)e * 256 + cb2) = c1;
    *(f4*)(conn + (size_t)e * 256 + cb2 + 4) = c2;
    part += __shfl_xor(part, 1);
    part += __shfl_xor(part, 2);
    if (dg == 0) score[(size_t)e * 8 + h] = fminf(fmaxf(part, -5.f), 5.f);
  }
}

// ---------- CSR build (by destination) ----------
__global__ void hist_k(const int* __restrict__ ei, int* __restrict__ cnt)
{
  int e = blockIdx.x * 256 + threadIdx.x;
  if (e < NE) atomicAdd(&cnt[ei[NE + e]], 1);
}

__global__ __launch_bounds__(256) void scan_k(const int* __restrict__ cnt, int* __restrict__ off)
{
  __shared__ int part[256];
  const int t = threadIdx.x;
  const int PER = 40;
  const int base = t * PER;
  int s = 0;
  for (int i = 0; i < PER; i++) {
    int b = base + i;
    if (b < NN) s += cnt[b];
  }
  part[t] = s;
  __syncthreads();
  for (int d = 1; d < 256; d <<= 1) {
    int v = (t >= d) ? part[t - d] : 0;
    __syncthreads();
    part[t] += v;
    __syncthreads();
  }
  int run = (t == 0) ? 0 : part[t - 1];
  for (int i = 0; i < PER; i++) {
    int b = base + i;
    if (b < NN) { off[b] = run; run += cnt[b]; }
  }
  if (t == 255) off[NN] = run;
}

__global__ void scat_k(const int* __restrict__ ei, const int* __restrict__ off,
                       int* __restrict__ cur, int* __restrict__ elist)
{
  int e = blockIdx.x * 256 + threadIdx.x;
  if (e < NE) {
    int d = ei[NE + e];
    int p = atomicAdd(&cur[d], 1);
    elist[off[d] + p] = e;
  }
}

// One block per node: online segment softmax + weighted aggregation + rowV einsum
__global__ __launch_bounds__(256) void node_agg_k(
    const int* __restrict__ off, const int* __restrict__ elist,
    const int* __restrict__ ei, const float* __restrict__ score,
    const float* __restrict__ Vh, const float* __restrict__ conn,
    const float* __restrict__ Qh, const float* __restrict__ VeRow,
    const float* __restrict__ deg_coef, const float* __restrict__ log_deg,
    float* __restrict__ nh_a)
{
  const int n = blockIdx.x, t = threadIdx.x;
  const int h = t >> 5;
  __shared__ int eL[128];
  __shared__ int srcL[128];
  __shared__ float sS[128 * 8];
  __shared__ float rA[256];
  const int start = off[n];
  const int deg = off[n + 1] - start;
  float m = -1e30f, ssum = 0.f, vo = 0.f, ro = 0.f;
  for (int c0 = 0; c0 < deg; c0 += 128) {
    const int cn = min(128, deg - c0);
    __syncthreads();
    if (t < cn) {
      int e = elist[start + c0 + t];
      eL[t] = e;
      srcL[t] = ei[e];
    }
    __syncthreads();
    for (int i = t; i < cn * 8; i += 256) sS[i] = score[(size_t)eL[i >> 3] * 8 + (i & 7)];
    __syncthreads();
    float mc = -1e30f;
    for (int i = 0; i < cn; i++) mc = fmaxf(mc, sS[i * 8 + h]);
    float nm = fmaxf(m, mc);
    float sc = __expf(m - nm);
    ssum *= sc; vo *= sc; ro *= sc;
    m = nm;
    for (int i = 0; i < cn; i++) {
      float w = __expf(sS[i * 8 + h] - m);
      ssum += w;
      vo = fmaf(w, Vh[(size_t)srcL[i] * 256 + t], vo);
      ro = fmaf(w, conn[(size_t)eL[i] * 256 + t], ro);
    }
  }
  const float inv = 1.f / (ssum + 1e-16f);
  vo *= inv;
  ro *= inv;
  __syncthreads();
  rA[t] = ro;
  __syncthreads();
  float acc = 0.f;
#pragma unroll
  for (int d = 0; d < 32; d++) acc = fmaf(rA[h * 32 + d], VeRow[d * 256 + t], acc);
  float v = Qh[(size_t)n * 256 + t] + vo + acc;
  const float ld = log_deg[n];
  v = v * (deg_coef[2 * t] + ld * deg_coef[2 * t + 1]);
  nh_a[(size_t)n * 256 + t] = v;
}

// eh = castbf16(conn) @ EowT^T + Eob + edge_attr, IN PLACE over conn (per-block rows),
// with fused bn1e stats (banked).
__global__ __launch_bounds__(256) void eh_gemm_k(
    const unsigned short* __restrict__ EowT, const float* __restrict__ Eob,
    const float* __restrict__ EA, float* __restrict__ eh, float* __restrict__ stb)
{
  __shared__ unsigned short Al[64][264];
  __shared__ unsigned short Bl[256][40];
  __shared__ float lsum[256], lsq[256];
  const int t = threadIdx.x;
  const int e0 = blockIdx.x * 64;
  const int lane = t & 63, c = lane & 15, g = lane >> 4, w = t >> 6;
  lsum[t] = 0.f; lsq[t] = 0.f;
  // stage full A (conn f32 -> bf16), rows e0..e0+63
#pragma unroll
  for (int it = 0; it < 8; it++) {
    int o = t + it * 256;
    int row = o >> 5, kk = (o & 31) * 8;
    const f4* p = (const f4*)(eh + (size_t)(e0 + row) * 256 + kk);
    f4 v0 = p[0], v1 = p[1];
    *(bf16x8*)&Al[row][kk] = pack8(v0, v1);
  }
  f32x4 acc[16] = {};
  for (int ks = 0; ks < 8; ks++) {
    __syncthreads();   // Bl reusable; first iter: Al ready
#pragma unroll
    for (int it = 0; it < 4; it++) {
      int o = t + it * 256;
      int row = o >> 2, kk = (o & 3) * 8;
      *(bf16x8*)&Bl[row][kk] = *(const bf16x8*)(EowT + (size_t)row * 256 + ks * 32 + kk);
    }
    __syncthreads();
    bf16x8 a = *(bf16x8*)&Al[w * 16 + c][ks * 32 + g * 8];
#pragma unroll
    for (int nb = 0; nb < 16; nb++) {
      bf16x8 b = *(bf16x8*)&Bl[nb * 16 + c][g * 8];
      acc[nb] = __builtin_amdgcn_mfma_f32_16x16x32_bf16(a, b, acc[nb], 0, 0, 0);
    }
  }
#pragma unroll
  for (int nb = 0; nb < 16; nb++) {
    const int col = nb * 16 + c;
    const float eob = Eob[col];
    float sn = 0.f, qn = 0.f;
#pragma unroll
    for (int r = 0; r < 4; r++) {
      size_t row = e0 + w * 16 + g * 4 + r;
      float v = acc[nb][r] + eob + EA[row * 256 + col];
      eh[row * 256 + col] = v;
      sn += v; qn += v * v;
    }
    sn += __shfl_xor(sn, 16); sn += __shfl_xor(sn, 32);
    qn += __shfl_xor(qn, 16); qn += __shfl_xor(qn, 32);
    if (g == 0) { atomicAdd(&lsum[col], sn); atomicAdd(&lsq[col], qn); }
  }
  __syncthreads();
  float* dstb = stb + (size_t)(blockIdx.x & 63) * 512;
  atomicAdd(&dstb[t], lsum[t]);
  atomicAdd(&dstb[256 + t], lsq[t]);
}

__global__ void bn_fin_k(float* __restrict__ st, float invR)
{
  int t = threadIdx.x;
  float mean = st[t] * invR;
  float var = st[256 + t] * invR - mean * mean;
  st[t] = mean;
  st[256 + t] = rsqrtf(var + 1e-5f);
}

__global__ void bn_fin_banked_k(const float* __restrict__ banks, float* __restrict__ st,
                                float invR)
{
  int t = threadIdx.x;
  float s = 0.f, q = 0.f;
  for (int b = 0; b < 64; b++) {
    s += banks[(size_t)b * 512 + t];
    q += banks[(size_t)b * 512 + 256 + t];
  }
  float mean = s * invR;
  float var = q * invR - mean * mean;
  st[t] = mean;
  st[256 + t] = rsqrtf(var + 1e-5f);
}

__global__ void bn_apply_k(const float* __restrict__ X, float* __restrict__ Y,
                           const float* __restrict__ st, const float* __restrict__ g,
                           const float* __restrict__ b, long nvec)
{
  long i = (long)blockIdx.x * 256 + threadIdx.x;
  if (i >= nvec) return;
  int base = (int)(i & 63) * 4;
  f4 x = *(const f4*)(X + i * 4);
  f4 mn = *(const f4*)(st + base);
  f4 rs = *(const f4*)(st + 256 + base);
  f4 gg = *(const f4*)(g + base);
  f4 bb = *(const f4*)(b + base);
  f4 y;
#pragma unroll
  for (int j = 0; j < 4; j++) y[j] = (x[j] - mn[j]) * rs[j] * gg[j] + bb[j];
  *(f4*)(Y + i * 4) = y;
}

extern "C" void kernel_launch(void* const* d_in, const int* in_sizes, int n_in,
                              void* d_out, int out_size, void* d_ws, size_t ws_size,
                              hipStream_t stream)
{
  (void)in_sizes; (void)n_in; (void)out_size; (void)ws_size;
  const float* x        = (const float*)d_in[0];
  const float* edge_attr= (const float*)d_in[1];
  const float* log_deg  = (const float*)d_in[2];
  const int*   ei       = (const int*)d_in[3];
  const float* Qw = (const float*)d_in[4];  const float* Qb = (const float*)d_in[5];
  const float* Kw = (const float*)d_in[6];  const float* Kb = (const float*)d_in[7];
  const float* Ew = (const float*)d_in[8];  const float* Eb = (const float*)d_in[9];
  const float* Vw = (const float*)d_in[10]; const float* Vb = (const float*)d_in[11];
  const float* Aw = (const float*)d_in[12]; const float* VeRow = (const float*)d_in[13];
  const float* deg_coef = (const float*)d_in[14];
  const float* Now = (const float*)d_in[15]; const float* Nob = (const float*)d_in[16];
  const float* Eow = (const float*)d_in[17]; const float* Eob = (const float*)d_in[18];
  const float* bn1n_g = (const float*)d_in[19]; const float* bn1n_b = (const float*)d_in[20];
  const float* bn1e_g = (const float*)d_in[21]; const float* bn1e_b = (const float*)d_in[22];
  const float* f1w = (const float*)d_in[23]; const float* f1b = (const float*)d_in[24];
  const float* f2w = (const float*)d_in[25]; const float* f2b = (const float*)d_in[26];
  const float* bn2_g = (const float*)d_in[27]; const float* bn2_b = (const float*)d_in[28];

  float* out_nh = (float*)d_out;
  float* out_eh = out_nh + (size_t)NN * 256;   // conn f32 lives here, becomes eh

  float* ws     = (float*)d_ws;
  float* Qh     = ws;                          // 2.56M each
  float* Kh     = Qh + 2560000;
  float* Vh     = Kh + 2560000;
  float* score  = Vh + 2560000;
  float* nh_a   = score + 2560000;
  float* nh2    = nh_a + 2560000;
  float* ffn1   = nh2 + 2560000;               // 5.12M
  float* st1    = ffn1 + 5120000;
  float* st2    = st1 + 512;
  float* st3    = st2 + 512;
  float* stb    = st3 + 512;                   // 64*512
  unsigned short* QwT = (unsigned short*)(stb + 64 * 512);
  unsigned short* KwT = QwT + 65536;
  unsigned short* VwT = KwT + 65536;
  unsigned short* NowT= VwT + 65536;
  unsigned short* EowT= NowT + 65536;
  unsigned short* EwT = EowT + 65536;          // 131072
  unsigned short* f1wT= EwT + 131072;          // 131072
  unsigned short* f2wT= f1wT + 131072;         // 131072
  int*   cnt    = (int*)(f2wT + 131072);
  int*   off    = cnt + NN;                    // NN+1
  int*   cur    = off + NN + 1;
  int*   elist  = cur + NN;                    // NE

  hipMemsetAsync(cnt, 0, (size_t)NN * 4, stream);
  hipMemsetAsync(cur, 0, (size_t)NN * 4, stream);
  hipMemsetAsync(st1, 0, (size_t)2 * 512 * 4, stream);
  hipMemsetAsync(stb, 0, (size_t)64 * 512 * 4, stream);

  dim3 blk(256);

  // weight transpose+cast
  castw_k<<<dim3(256), blk, 0, stream>>>(Qw, QwT, 256, 8);
  castw_k<<<dim3(256), blk, 0, stream>>>(Kw, KwT, 256, 8);
  castw_k<<<dim3(256), blk, 0, stream>>>(Vw, VwT, 256, 8);
  castw_k<<<dim3(256), blk, 0, stream>>>(Now, NowT, 256, 8);
  castw_k<<<dim3(256), blk, 0, stream>>>(Eow, EowT, 256, 8);
  castw_k<<<dim3(512), blk, 0, stream>>>(Ew, EwT, 256, 9);
  castw_k<<<dim3(512), blk, 0, stream>>>(f1w, f1wT, 256, 9);
  castw_k<<<dim3(512), blk, 0, stream>>>(f2w, f2wT, 512, 8);

  // CSR build
  hist_k<<<dim3(NE / 256), blk, 0, stream>>>(ei, cnt);
  scan_k<<<dim3(1), blk, 0, stream>>>(cnt, off);
  scat_k<<<dim3(NE / 256), blk, 0, stream>>>(ei, off, cur, elist);

  // QKV projections (MFMA)
  gemm_bf16_k<<<dim3(2, 157), blk, 0, stream>>>(x, QwT, Qb, nullptr, Qh, nullptr,
                                                NN, 256, 256, 0);
  gemm_bf16_k<<<dim3(2, 157), blk, 0, stream>>>(x, KwT, Kb, nullptr, Kh, nullptr,
                                                NN, 256, 256, 0);
  gemm_bf16_k<<<dim3(2, 157), blk, 0, stream>>>(x, VwT, Vb, nullptr, Vh, nullptr,
                                                NN, 256, 256, 0);

  // edge conn + score (MFMA)
  edge_conn_k<<<dim3(NE / 64), blk, 0, stream>>>(edge_attr, EwT, Eb, Kh, Qh, ei, Aw,
                                                 out_eh, score);

  // per-node segment softmax + aggregation (reads conn f32)
  node_agg_k<<<dim3(NN), blk, 0, stream>>>(off, elist, ei, score, Vh, out_eh,
                                           Qh, VeRow, deg_coef, log_deg, nh_a);

  // eh = conn @ Eow + Eob + edge_attr (in place) + fused bn1e stats
  eh_gemm_k<<<dim3(NE / 64), blk, 0, stream>>>(EowT, Eob, edge_attr, out_eh, stb);
  bn_fin_banked_k<<<dim3(1), blk, 0, stream>>>(stb, st3, 1.0f / NE);
  bn_apply_k<<<dim3(NE * 64 / 256), blk, 0, stream>>>(out_eh, out_eh, st3,
                                                      bn1e_g, bn1e_b, (long)NE * 64);

  // node path: nh1 = nh_a @ Now + Nob + x (+bn1n stats)
  gemm_bf16_k<<<dim3(2, 157), blk, 0, stream>>>(nh_a, NowT, Nob, x, out_nh, st1,
                                                NN, 256, 256, 2);
  bn_fin_k<<<dim3(1), blk, 0, stream>>>(st1, 1.0f / NN);
  bn_apply_k<<<dim3(NN * 64 / 256), blk, 0, stream>>>(out_nh, nh2, st1,
                                                      bn1n_g, bn1n_b, (long)NN * 64);
  // FFN
  gemm_bf16_k<<<dim3(4, 157), blk, 0, stream>>>(nh2, f1wT, f1b, nullptr, ffn1, nullptr,
                                                NN, 256, 512, 1);
  gemm_bf16_k<<<dim3(2, 157), blk, 0, stream>>>(ffn1, f2wT, f2b, nh2, out_nh, st2,
                                                NN, 512, 256, 2);
  bn_fin_k<<<dim3(1), blk, 0, stream>>>(st2, 1.0f / NN);
  bn_apply_k<<<dim3(NN * 64 / 256), blk, 0, stream>>>(out_nh, out_nh, st2,
                                                      bn2_g, bn2_b, (long)NN * 64);
}